// Round 2
// baseline (109.892 us; speedup 1.0000x reference)
//
#include <hip/hip_runtime.h>

#define MARGIN 0.3f

typedef __attribute__((ext_vector_type(8))) short short8;
typedef __attribute__((ext_vector_type(4))) float floatx4;

// ---- helpers ----------------------------------------------------------------

// order-preserving float->uint encoding so unsigned atomicMin == float min
__device__ __forceinline__ unsigned enc_f32(float f) {
    unsigned u = __float_as_uint(f);
    return (u & 0x80000000u) ? ~u : (u | 0x80000000u);
}
__device__ __forceinline__ float dec_f32(unsigned u) {
    return (u & 0x80000000u) ? __uint_as_float(u & 0x7fffffffu)
                             : __uint_as_float(~u);
}
// fp32 -> bf16 bits, round-to-nearest-even
__device__ __forceinline__ short f2bf(float f) {
    unsigned u = __float_as_uint(f);
    u = u + 0x7fffu + ((u >> 16) & 1u);
    return (short)(u >> 16);
}

// direct global->LDS DMA (no VGPR round-trip). LDS dest is wave-uniform
// base + lane*size — all call sites below are thread-linear.
__device__ __forceinline__ void gload_lds16(const void* g, void* l) {
    __builtin_amdgcn_global_load_lds(
        (const __attribute__((address_space(1))) void*)g,
        (__attribute__((address_space(3))) void*)l, 16, 0, 0);
}
__device__ __forceinline__ void gload_lds4(const void* g, void* l) {
    __builtin_amdgcn_global_load_lds(
        (const __attribute__((address_space(1))) void*)g,
        (__attribute__((address_space(3))) void*)l, 4, 0, 0);
}

// Fragment-native global layout: element (row, k) with g16=row/16, r=row%16,
// kk=k/32, q=(k%32)/8, e=k%8 lives at  g16*2048 + kk*512 + q*128 + r*8 + e.
// A wave's fragment load for (g16, kk) is base + lane*8 shorts = 64 lanes x
// 16 B CONTIGUOUS — the global->LDS stage is a linear memcpy.

// ---- kernel 1: prepass (unchanged) ------------------------------------------
__global__ void prep_kernel(const float* __restrict__ z1, const float* __restrict__ z2,
                            short* __restrict__ z1b, short* __restrict__ z2b,
                            float* __restrict__ sq1, float* __restrict__ sq2,
                            float* __restrict__ posd, unsigned* __restrict__ rowmin,
                            unsigned* __restrict__ cnt, float* __restrict__ out) {
    int h = blockIdx.x * 256 + threadIdx.x;     // 0 .. n*16-1
    int row = h >> 4, p = h & 15;
    int kk = p >> 2, q = p & 3;
    int f0 = row * 32 + kk * 8 + q * 2;         // first float4 index
    float4 fa0 = ((const float4*)z1)[f0], fa1 = ((const float4*)z1)[f0 + 1];
    float4 fb0 = ((const float4*)z2)[f0], fb1 = ((const float4*)z2)[f0 + 1];
    short8 sa = { f2bf(fa0.x), f2bf(fa0.y), f2bf(fa0.z), f2bf(fa0.w),
                  f2bf(fa1.x), f2bf(fa1.y), f2bf(fa1.z), f2bf(fa1.w) };
    short8 sb = { f2bf(fb0.x), f2bf(fb0.y), f2bf(fb0.z), f2bf(fb0.w),
                  f2bf(fb1.x), f2bf(fb1.y), f2bf(fb1.z), f2bf(fb1.w) };
    size_t off = (size_t)(row >> 4) * 2048 + kk * 512 + q * 128 + (row & 15) * 8;
    *(short8*)&z1b[off] = sa;
    *(short8*)&z2b[off] = sb;

    float s1 = fa0.x*fa0.x + fa0.y*fa0.y + fa0.z*fa0.z + fa0.w*fa0.w
             + fa1.x*fa1.x + fa1.y*fa1.y + fa1.z*fa1.z + fa1.w*fa1.w;
    float s2 = fb0.x*fb0.x + fb0.y*fb0.y + fb0.z*fb0.z + fb0.w*fb0.w
             + fb1.x*fb1.x + fb1.y*fb1.y + fb1.z*fb1.z + fb1.w*fb1.w;
    float dx0 = fa0.x-fb0.x, dy0 = fa0.y-fb0.y, dz0 = fa0.z-fb0.z, dw0 = fa0.w-fb0.w;
    float dx1 = fa1.x-fb1.x, dy1 = fa1.y-fb1.y, dz1 = fa1.z-fb1.z, dw1 = fa1.w-fb1.w;
    float p2 = dx0*dx0 + dy0*dy0 + dz0*dz0 + dw0*dw0
             + dx1*dx1 + dy1*dy1 + dz1*dz1 + dw1*dw1;
    #pragma unroll
    for (int m = 8; m >= 1; m >>= 1) {          // 16 threads per row
        s1 += __shfl_xor(s1, m);
        s2 += __shfl_xor(s2, m);
        p2 += __shfl_xor(p2, m);
    }
    if (p == 0) { sq1[row] = s1; sq2[row] = s2; posd[row] = sqrtf(p2); }

    if (threadIdx.x < 16) rowmin[blockIdx.x * 16 + threadIdx.x] = 0xFFFFFFFFu;
    if (blockIdx.x == 0) {
        if (threadIdx.x < 32) cnt[threadIdx.x] = 0u;
        if (threadIdx.x == 0) out[0] = 0.0f;
    }
}

// ---- kernel 2: full-panel-prefetch MFMA GEMM + row-min + fused loss ---------
// grid (32, 32): rg = 256-row group (4 waves x 64 rows), cgi = 256-col group.
// The block's ENTIRE B panel (256 cols x 128 k = 64 KB) is issued to LDS in
// the prologue as 4 x 16 KB buffers (33 outstanding vmem/wave, < 63 cap).
// The main loop has ZERO global traffic: superphase s waits vmcnt(4*(3-s))
// (12/8/4/0) so later buffers stay in flight — memory latency is paid once,
// in the prologue, overlapped across 2 resident blocks/CU. Buffers are never
// reused -> barriers are stage-visibility only, no WAR hazards.
__global__ __launch_bounds__(256, 2)
void gemm_min_kernel(const short* __restrict__ z1b, const short* __restrict__ z2b,
                     const float* __restrict__ sq1, const float* __restrict__ sq2,
                     const float* __restrict__ posd,
                     unsigned* __restrict__ rowmin, unsigned* __restrict__ cnt,
                     float* __restrict__ out, int n)
{
    __shared__ __align__(16) short sb[4][8192];   // 4 x (64 cols x 128 k) bf16
    __shared__ __align__(16) float s2l[256];      // sq2 slice for block's cols
    __shared__ float lsum[4];
    __shared__ int   fin_s;

    const int rg = blockIdx.y, cgi = blockIdx.x;
    const int tid = threadIdx.x, w = tid >> 6, lane = tid & 63;
    const int quad = lane >> 4, l15 = lane & 15;
    const int rowbase = rg * 256 + w * 64;      // this wave's 64 rows
    const int colorig = cgi * 256;

    const short* gb = z2b + (size_t)(cgi * 16) * 2048;   // block's B panel

    // ---- prologue: issue EVERYTHING. vmem issue order (per wave, uniform):
    //   buf0 (4) | s2l (1) | af (16) | buf1 (4) | buf2 (4) | buf3 (4) = 33.
    // sched_barrier(0) pins group order so counted vmcnt stays sound.
    #pragma unroll
    for (int o = 0; o < 4; ++o)
        gload_lds16(gb + (tid + o * 256) * 8, &sb[0][(tid + o * 256) * 8]);
    __builtin_amdgcn_sched_barrier(0);
    gload_lds4(sq2 + colorig + tid, &s2l[tid]);
    __builtin_amdgcn_sched_barrier(0);

    // persistent A fragments: af[sm][kk] = A[m = l15 + sm*16 (+rowbase)][kk*32+quad*8 ..+7]
    short8 af[4][4];
    #pragma unroll
    for (int sm = 0; sm < 4; ++sm) {
        const short* pa = z1b + (size_t)(rg * 16 + w * 4 + sm) * 2048 + lane * 8;
        #pragma unroll
        for (int kk = 0; kk < 4; ++kk)
            af[sm][kk] = *(const short8*)(pa + kk * 512);
    }
    __builtin_amdgcn_sched_barrier(0);
    #pragma unroll
    for (int s = 1; s < 4; ++s) {
        #pragma unroll
        for (int o = 0; o < 4; ++o)
            gload_lds16(gb + (size_t)s * 8192 + (tid + o * 256) * 8,
                        &sb[s][(tid + o * 256) * 8]);
        __builtin_amdgcn_sched_barrier(0);
    }

    float vmin[4][4];
    #pragma unroll
    for (int sm = 0; sm < 4; ++sm)
        #pragma unroll
        for (int reg = 0; reg < 4; ++reg)
            vmin[sm][reg] = 3.0e38f;

    // superphase S: wait own stage loads for buf S (counted — later bufs stay
    // in flight), barrier for cross-wave visibility, then pure LDS+MFMA+VALU.
#define SUPERPHASE(S, VMTXT)                                                   \
    do {                                                                       \
        asm volatile("s_waitcnt vmcnt(" VMTXT ")" ::: "memory");               \
        __builtin_amdgcn_sched_barrier(0);                                     \
        __builtin_amdgcn_s_barrier();                                          \
        __builtin_amdgcn_sched_barrier(0);                                     \
        const short* bs_ = &sb[S][0];                                          \
        _Pragma("unroll")                                                      \
        for (int hf = 0; hf < 2; ++hf) {                                       \
            const int tcol = (S) * 64 + hf * 32;                               \
            const int colbase = colorig + tcol;                                \
            const float s2v0 = s2l[tcol + l15];                                \
            const float s2v1 = s2l[tcol + 16 + l15];                           \
            short8 bq[2][4];                                                   \
            _Pragma("unroll")                                                  \
            for (int sn = 0; sn < 2; ++sn)                                     \
                _Pragma("unroll")                                              \
                for (int kk = 0; kk < 4; ++kk)                                 \
                    bq[sn][kk] = *(const short8*)(bs_ + hf * 4096 + sn * 2048  \
                                                  + kk * 512 + lane * 8);      \
            floatx4 acc[4][2];                                                 \
            _Pragma("unroll")                                                  \
            for (int sm = 0; sm < 4; ++sm)                                     \
                _Pragma("unroll")                                              \
                for (int sn = 0; sn < 2; ++sn)                                 \
                    acc[sm][sn] = (floatx4)0.0f;                               \
            _Pragma("unroll")                                                  \
            for (int kk = 0; kk < 4; ++kk)                                     \
                _Pragma("unroll")                                              \
                for (int sm = 0; sm < 4; ++sm)                                 \
                    _Pragma("unroll")                                          \
                    for (int sn = 0; sn < 2; ++sn)                             \
                        acc[sm][sn] = __builtin_amdgcn_mfma_f32_16x16x32_bf16( \
                            af[sm][kk], bq[sn][kk], acc[sm][sn], 0, 0, 0);     \
            if (colbase < rowbase + 64 && rowbase < colbase + 32) {            \
                _Pragma("unroll")                                              \
                for (int sm = 0; sm < 4; ++sm)                                 \
                    _Pragma("unroll")                                          \
                    for (int reg = 0; reg < 4; ++reg) {                        \
                        int gi = rowbase + sm * 16 + quad * 4 + reg;           \
                        float v0 = fmaf(-2.0f, acc[sm][0][reg], s2v0);         \
                        float v1 = fmaf(-2.0f, acc[sm][1][reg], s2v1);         \
                        v0 = (gi == colbase + l15)      ? 3.0e38f : v0;        \
                        v1 = (gi == colbase + 16 + l15) ? 3.0e38f : v1;        \
                        vmin[sm][reg] = fminf(vmin[sm][reg], fminf(v0, v1));   \
                    }                                                          \
            } else {                                                           \
                _Pragma("unroll")                                              \
                for (int sm = 0; sm < 4; ++sm)                                 \
                    _Pragma("unroll")                                          \
                    for (int reg = 0; reg < 4; ++reg) {                        \
                        float v0 = fmaf(-2.0f, acc[sm][0][reg], s2v0);         \
                        float v1 = fmaf(-2.0f, acc[sm][1][reg], s2v1);         \
                        vmin[sm][reg] = fminf(vmin[sm][reg], fminf(v0, v1));   \
                    }                                                          \
            }                                                                  \
        }                                                                      \
    } while (0)

    SUPERPHASE(0, "12");
    SUPERPHASE(1, "8");
    SUPERPHASE(2, "4");
    SUPERPHASE(3, "0");
#undef SUPERPHASE

    // min across each quad's 16 lanes, one atomicMin per row
    #pragma unroll
    for (int sm = 0; sm < 4; ++sm)
        #pragma unroll
        for (int reg = 0; reg < 4; ++reg) {
            float vm = vmin[sm][reg];
            #pragma unroll
            for (int m = 8; m >= 1; m >>= 1)
                vm = fminf(vm, __shfl_xor(vm, m));
            if (l15 == 0)
                atomicMin(&rowmin[rowbase + sm * 16 + quad * 4 + reg], enc_f32(vm));
        }

    __syncthreads();
    if (tid == 0) {
        __threadfence();    // release: this block's mins visible before bump
        fin_s = (atomicAdd(&cnt[rg], 1u) == 31u);   // 32 col-blocks per rg
    }
    __syncthreads();
    if (!fin_s) return;
    __threadfence();        // acquire: see all 32 blocks' mins

    // fused loss for rows [rg*256, rg*256+256): thread = one row
    {
        int i = rg * 256 + tid;
        unsigned rm = atomicMin(&rowmin[i], 0xFFFFFFFFu);   // coherent forced read
        float hard = sqrtf(fmaxf(sq1[i] + dec_f32(rm), 0.0f));
        float l = fmaxf(posd[i] - hard + MARGIN, 0.0f);
        #pragma unroll
        for (int m = 32; m >= 1; m >>= 1) l += __shfl_xor(l, m);
        if (lane == 0) lsum[w] = l;
    }
    __syncthreads();
    if (tid == 0)
        atomicAdd(out, (lsum[0] + lsum[1] + lsum[2] + lsum[3]) / (float)n);
}

// ---- launch -----------------------------------------------------------------
extern "C" void kernel_launch(void* const* d_in, const int* in_sizes, int n_in,
                              void* d_out, int out_size, void* d_ws, size_t ws_size,
                              hipStream_t stream) {
    const float* z1 = (const float*)d_in[0];
    const float* z2 = (const float*)d_in[1];
    const int n = in_sizes[0] / 128;            // 8192

    char* ws = (char*)d_ws;
    short*    z1b    = (short*)ws;                                     // 2 MB
    short*    z2b    = (short*)(ws + (size_t)n * 128 * 2);             // 2 MB
    float*    sq1    = (float*)(ws + (size_t)n * 128 * 4);             // 32 KB
    float*    sq2    = (float*)(ws + (size_t)n * 128 * 4 + n * 4);     // 32 KB
    float*    posd   = (float*)(ws + (size_t)n * 128 * 4 + n * 8);     // 32 KB
    unsigned* rowmin = (unsigned*)(ws + (size_t)n * 128 * 4 + n * 12); // 32 KB
    unsigned* cnt    = (unsigned*)(ws + (size_t)n * 128 * 4 + n * 16); // 128 B
    float*    out    = (float*)d_out;

    prep_kernel<<<n / 16, 256, 0, stream>>>(z1, z2, z1b, z2b, sq1, sq2, posd,
                                            rowmin, cnt, out);
    dim3 grid(n / 256, n / 256);                // (colgroups, rowgroups)
    gemm_min_kernel<<<grid, 256, 0, stream>>>(z1b, z2b, sq1, sq2, posd,
                                              rowmin, cnt, out, n);
}

// Round 3
// 83.960 us; speedup vs baseline: 1.3089x; 1.3089x over previous
//
#include <hip/hip_runtime.h>

#define MARGIN 0.3f

typedef __attribute__((ext_vector_type(8))) short short8;
typedef __attribute__((ext_vector_type(4))) float floatx4;

// ---- helpers ----------------------------------------------------------------

// order-preserving float->uint encoding so unsigned atomicMin == float min
__device__ __forceinline__ unsigned enc_f32(float f) {
    unsigned u = __float_as_uint(f);
    return (u & 0x80000000u) ? ~u : (u | 0x80000000u);
}
__device__ __forceinline__ float dec_f32(unsigned u) {
    return (u & 0x80000000u) ? __uint_as_float(u & 0x7fffffffu)
                             : __uint_as_float(~u);
}
// fp32 -> bf16 bits, round-to-nearest-even
__device__ __forceinline__ short f2bf(float f) {
    unsigned u = __float_as_uint(f);
    u = u + 0x7fffu + ((u >> 16) & 1u);
    return (short)(u >> 16);
}

// direct global->LDS DMA (no VGPR round-trip). LDS dest is wave-uniform
// base + lane*size — all call sites below are thread-linear.
__device__ __forceinline__ void gload_lds16(const void* g, void* l) {
    __builtin_amdgcn_global_load_lds(
        (const __attribute__((address_space(1))) void*)g,
        (__attribute__((address_space(3))) void*)l, 16, 0, 0);
}
__device__ __forceinline__ void gload_lds4(const void* g, void* l) {
    __builtin_amdgcn_global_load_lds(
        (const __attribute__((address_space(1))) void*)g,
        (__attribute__((address_space(3))) void*)l, 4, 0, 0);
}

// Fragment-native global layout: element (row, k) with g16=row/16, r=row%16,
// kk=k/32, q=(k%32)/8, e=k%8 lives at  g16*2048 + kk*512 + q*128 + r*8 + e.
// A wave's fragment load for (g16, kk) is base + lane*8 shorts = 64 lanes x
// 16 B CONTIGUOUS — the global->LDS stage is a linear memcpy.

// ---- kernel 1: prepass (unchanged) ------------------------------------------
__global__ void prep_kernel(const float* __restrict__ z1, const float* __restrict__ z2,
                            short* __restrict__ z1b, short* __restrict__ z2b,
                            float* __restrict__ sq1, float* __restrict__ sq2,
                            float* __restrict__ posd, unsigned* __restrict__ rowmin,
                            unsigned* __restrict__ cnt, float* __restrict__ out) {
    int h = blockIdx.x * 256 + threadIdx.x;     // 0 .. n*16-1
    int row = h >> 4, p = h & 15;
    int kk = p >> 2, q = p & 3;
    int f0 = row * 32 + kk * 8 + q * 2;         // first float4 index
    float4 fa0 = ((const float4*)z1)[f0], fa1 = ((const float4*)z1)[f0 + 1];
    float4 fb0 = ((const float4*)z2)[f0], fb1 = ((const float4*)z2)[f0 + 1];
    short8 sa = { f2bf(fa0.x), f2bf(fa0.y), f2bf(fa0.z), f2bf(fa0.w),
                  f2bf(fa1.x), f2bf(fa1.y), f2bf(fa1.z), f2bf(fa1.w) };
    short8 sb = { f2bf(fb0.x), f2bf(fb0.y), f2bf(fb0.z), f2bf(fb0.w),
                  f2bf(fb1.x), f2bf(fb1.y), f2bf(fb1.z), f2bf(fb1.w) };
    size_t off = (size_t)(row >> 4) * 2048 + kk * 512 + q * 128 + (row & 15) * 8;
    *(short8*)&z1b[off] = sa;
    *(short8*)&z2b[off] = sb;

    float s1 = fa0.x*fa0.x + fa0.y*fa0.y + fa0.z*fa0.z + fa0.w*fa0.w
             + fa1.x*fa1.x + fa1.y*fa1.y + fa1.z*fa1.z + fa1.w*fa1.w;
    float s2 = fb0.x*fb0.x + fb0.y*fb0.y + fb0.z*fb0.z + fb0.w*fb0.w
             + fb1.x*fb1.x + fb1.y*fb1.y + fb1.z*fb1.z + fb1.w*fb1.w;
    float dx0 = fa0.x-fb0.x, dy0 = fa0.y-fb0.y, dz0 = fa0.z-fb0.z, dw0 = fa0.w-fb0.w;
    float dx1 = fa1.x-fb1.x, dy1 = fa1.y-fb1.y, dz1 = fa1.z-fb1.z, dw1 = fa1.w-fb1.w;
    float p2 = dx0*dx0 + dy0*dy0 + dz0*dz0 + dw0*dw0
             + dx1*dx1 + dy1*dy1 + dz1*dz1 + dw1*dw1;
    #pragma unroll
    for (int m = 8; m >= 1; m >>= 1) {          // 16 threads per row
        s1 += __shfl_xor(s1, m);
        s2 += __shfl_xor(s2, m);
        p2 += __shfl_xor(p2, m);
    }
    if (p == 0) { sq1[row] = s1; sq2[row] = s2; posd[row] = sqrtf(p2); }

    if (threadIdx.x < 16) rowmin[blockIdx.x * 16 + threadIdx.x] = 0xFFFFFFFFu;
    if (blockIdx.x == 0) {
        if (threadIdx.x < 32) cnt[threadIdx.x] = 0u;
        if (threadIdx.x == 0) out[0] = 0.0f;
    }
}

// ---- kernel 2: 512x512-tile full-panel MFMA GEMM + row-min + fused loss -----
// grid 256 linear = EXACTLY 1 block/CU (single pass). Block = 512 threads =
// 8 waves; wave w owns 64 rows. XCD-bijective swizzle: xcd = bid%8 owns
// row-groups {2*xcd, 2*xcd+1} x all 16 col-groups -> per-XCD working set
// (2 A-panels 256 KB + B 2 MB) < 4 MB L2: B re-reads become L2 hits.
// B panel (512 cols x 128 k = 128 KB) fully issued in prologue as 8 x 16 KB
// LDS buffers; superphase S waits vmcnt(2*(7-S)) — later buffers stay in
// flight, memory latency is paid exactly once. Zero global traffic in loop.
__global__ __launch_bounds__(512, 2)
void gemm_min_kernel(const short* __restrict__ z1b, const short* __restrict__ z2b,
                     const float* __restrict__ sq1, const float* __restrict__ sq2,
                     const float* __restrict__ posd,
                     unsigned* __restrict__ rowmin, unsigned* __restrict__ cnt,
                     float* __restrict__ out, int n)
{
    __shared__ __align__(16) short sb[8][8192];   // 8 x (64 cols x 128 k) bf16
    __shared__ __align__(16) float s2l[512];      // sq2 slice for block's cols
    __shared__ float lsum[8];
    __shared__ int   fin_s;

    // bijective XCD swizzle (256 blocks = 8 xcd x 32, exact)
    const int bid = blockIdx.x;
    const int xcd = bid & 7, idx = bid >> 3;      // idx 0..31
    const int rg  = (xcd << 1) | (idx >> 4);      // row-group 0..15
    const int cgi = idx & 15;                     // col-group 0..15

    const int tid = threadIdx.x, w = tid >> 6, lane = tid & 63;
    const int quad = lane >> 4, l15 = lane & 15;
    const int rowbase = rg * 512 + w * 64;        // this wave's 64 rows
    const int colorig = cgi * 512;

    const short* gb = z2b + (size_t)(cgi * 32) * 2048;   // block's B panel

    // ---- prologue: issue EVERYTHING. vmem issue order (per wave, uniform):
    //   buf0 (2) | s2l (1) | af (16) | buf1..7 (2 each) = 33 outstanding.
    // sched_barrier(0) pins group order so counted vmcnt stays sound.
    #pragma unroll
    for (int o = 0; o < 2; ++o)
        gload_lds16(gb + (tid + o * 512) * 8, &sb[0][(tid + o * 512) * 8]);
    __builtin_amdgcn_sched_barrier(0);
    gload_lds4(sq2 + colorig + tid, &s2l[tid]);
    __builtin_amdgcn_sched_barrier(0);

    // persistent A fragments: af[sm][kk] = A[m = l15 + sm*16 (+rowbase)][kk*32+quad*8 ..+7]
    short8 af[4][4];
    #pragma unroll
    for (int sm = 0; sm < 4; ++sm) {
        const short* pa = z1b + (size_t)(rg * 32 + w * 4 + sm) * 2048 + lane * 8;
        #pragma unroll
        for (int kk = 0; kk < 4; ++kk)
            af[sm][kk] = *(const short8*)(pa + kk * 512);
    }
    __builtin_amdgcn_sched_barrier(0);
    #pragma unroll
    for (int s = 1; s < 8; ++s) {
        #pragma unroll
        for (int o = 0; o < 2; ++o)
            gload_lds16(gb + (size_t)s * 8192 + (tid + o * 512) * 8,
                        &sb[s][(tid + o * 512) * 8]);
        __builtin_amdgcn_sched_barrier(0);
    }

    float vmin[4][4];
    #pragma unroll
    for (int sm = 0; sm < 4; ++sm)
        #pragma unroll
        for (int reg = 0; reg < 4; ++reg)
            vmin[sm][reg] = 3.0e38f;

    // superphase S: wait own stage loads for buf S (counted — later bufs stay
    // in flight), barrier for cross-wave visibility, then pure LDS+MFMA+VALU.
#define SUPERPHASE(S, VMTXT)                                                   \
    do {                                                                       \
        asm volatile("s_waitcnt vmcnt(" VMTXT ")" ::: "memory");               \
        __builtin_amdgcn_sched_barrier(0);                                     \
        __builtin_amdgcn_s_barrier();                                          \
        __builtin_amdgcn_sched_barrier(0);                                     \
        const short* bs_ = &sb[S][0];                                          \
        _Pragma("unroll")                                                      \
        for (int hf = 0; hf < 2; ++hf) {                                       \
            const int tcol = (S) * 64 + hf * 32;                               \
            const int colbase = colorig + tcol;                                \
            const float s2v0 = s2l[tcol + l15];                                \
            const float s2v1 = s2l[tcol + 16 + l15];                           \
            short8 bq[2][4];                                                   \
            _Pragma("unroll")                                                  \
            for (int sn = 0; sn < 2; ++sn)                                     \
                _Pragma("unroll")                                              \
                for (int kk = 0; kk < 4; ++kk)                                 \
                    bq[sn][kk] = *(const short8*)(bs_ + hf * 4096 + sn * 2048  \
                                                  + kk * 512 + lane * 8);      \
            floatx4 acc[4][2];                                                 \
            _Pragma("unroll")                                                  \
            for (int sm = 0; sm < 4; ++sm)                                     \
                _Pragma("unroll")                                              \
                for (int sn = 0; sn < 2; ++sn)                                 \
                    acc[sm][sn] = (floatx4)0.0f;                               \
            _Pragma("unroll")                                                  \
            for (int kk = 0; kk < 4; ++kk)                                     \
                _Pragma("unroll")                                              \
                for (int sm = 0; sm < 4; ++sm)                                 \
                    _Pragma("unroll")                                          \
                    for (int sn = 0; sn < 2; ++sn)                             \
                        acc[sm][sn] = __builtin_amdgcn_mfma_f32_16x16x32_bf16( \
                            af[sm][kk], bq[sn][kk], acc[sm][sn], 0, 0, 0);     \
            if (colbase < rowbase + 64 && rowbase < colbase + 32) {            \
                _Pragma("unroll")                                              \
                for (int sm = 0; sm < 4; ++sm)                                 \
                    _Pragma("unroll")                                          \
                    for (int reg = 0; reg < 4; ++reg) {                        \
                        int gi = rowbase + sm * 16 + quad * 4 + reg;           \
                        float v0 = fmaf(-2.0f, acc[sm][0][reg], s2v0);         \
                        float v1 = fmaf(-2.0f, acc[sm][1][reg], s2v1);         \
                        v0 = (gi == colbase + l15)      ? 3.0e38f : v0;        \
                        v1 = (gi == colbase + 16 + l15) ? 3.0e38f : v1;        \
                        vmin[sm][reg] = fminf(vmin[sm][reg], fminf(v0, v1));   \
                    }                                                          \
            } else {                                                           \
                _Pragma("unroll")                                              \
                for (int sm = 0; sm < 4; ++sm)                                 \
                    _Pragma("unroll")                                          \
                    for (int reg = 0; reg < 4; ++reg) {                        \
                        float v0 = fmaf(-2.0f, acc[sm][0][reg], s2v0);         \
                        float v1 = fmaf(-2.0f, acc[sm][1][reg], s2v1);         \
                        vmin[sm][reg] = fminf(vmin[sm][reg], fminf(v0, v1));   \
                    }                                                          \
            }                                                                  \
        }                                                                      \
    } while (0)

    SUPERPHASE(0, "14");
    SUPERPHASE(1, "12");
    SUPERPHASE(2, "10");
    SUPERPHASE(3, "8");
    SUPERPHASE(4, "6");
    SUPERPHASE(5, "4");
    SUPERPHASE(6, "2");
    SUPERPHASE(7, "0");
#undef SUPERPHASE

    // min across each quad's 16 lanes, one atomicMin per row
    #pragma unroll
    for (int sm = 0; sm < 4; ++sm)
        #pragma unroll
        for (int reg = 0; reg < 4; ++reg) {
            float vm = vmin[sm][reg];
            #pragma unroll
            for (int m = 8; m >= 1; m >>= 1)
                vm = fminf(vm, __shfl_xor(vm, m));
            if (l15 == 0)
                atomicMin(&rowmin[rowbase + sm * 16 + quad * 4 + reg], enc_f32(vm));
        }

    __syncthreads();
    if (tid == 0) {
        __threadfence();    // release: this block's mins visible before bump
        fin_s = (atomicAdd(&cnt[rg], 1u) == 15u);   // 16 col-blocks per rg
    }
    __syncthreads();
    if (!fin_s) return;
    __threadfence();        // acquire: see all 16 blocks' mins

    // fused loss for rows [rg*512, rg*512+512): thread = one row
    {
        int i = rg * 512 + tid;
        unsigned rm = atomicMin(&rowmin[i], 0xFFFFFFFFu);   // coherent forced read
        float hard = sqrtf(fmaxf(sq1[i] + dec_f32(rm), 0.0f));
        float l = fmaxf(posd[i] - hard + MARGIN, 0.0f);
        #pragma unroll
        for (int m = 32; m >= 1; m >>= 1) l += __shfl_xor(l, m);
        if (lane == 0) lsum[w] = l;
    }
    __syncthreads();
    if (tid == 0) {
        float t = 0.f;
        #pragma unroll
        for (int i = 0; i < 8; ++i) t += lsum[i];
        atomicAdd(out, t / (float)n);
    }
}

// ---- launch -----------------------------------------------------------------
extern "C" void kernel_launch(void* const* d_in, const int* in_sizes, int n_in,
                              void* d_out, int out_size, void* d_ws, size_t ws_size,
                              hipStream_t stream) {
    const float* z1 = (const float*)d_in[0];
    const float* z2 = (const float*)d_in[1];
    const int n = in_sizes[0] / 128;            // 8192

    char* ws = (char*)d_ws;
    short*    z1b    = (short*)ws;                                     // 2 MB
    short*    z2b    = (short*)(ws + (size_t)n * 128 * 2);             // 2 MB
    float*    sq1    = (float*)(ws + (size_t)n * 128 * 4);             // 32 KB
    float*    sq2    = (float*)(ws + (size_t)n * 128 * 4 + n * 4);     // 32 KB
    float*    posd   = (float*)(ws + (size_t)n * 128 * 4 + n * 8);     // 32 KB
    unsigned* rowmin = (unsigned*)(ws + (size_t)n * 128 * 4 + n * 12); // 32 KB
    unsigned* cnt    = (unsigned*)(ws + (size_t)n * 128 * 4 + n * 16); // 128 B
    float*    out    = (float*)d_out;

    prep_kernel<<<n / 16, 256, 0, stream>>>(z1, z2, z1b, z2b, sq1, sq2, posd,
                                            rowmin, cnt, out);
    gemm_min_kernel<<<(n / 512) * (n / 512), 512, 0, stream>>>(
        z1b, z2b, sq1, sq2, posd, rowmin, cnt, out, n);
}